// Round 2
// baseline (7339.850 us; speedup 1.0000x reference)
//
#include <hip/hip_runtime.h>
#include <hip/hip_bf16.h>

// R2: dtype-robust correct-first implementation.
//   detect_dtype : classifies d_in float tensors as fp32 vs bf16 from bit patterns
//   to_bf16/to_f32: normalize weights (bf16 for MFMA) and biases/h0 (fp32) into ws
//   gemm_bt64    : xp = A @ W^T + b1 (+ b2); A-load and out-store flag-branched
//   rnn_recur    : 16 blocks = 8 groups x 2 col-halves; Whh half in VGPR B-frags;
//                  h halves exchanged via parity buffers + agent-scope flags.
//                  Blocks (g, g+8) pair so a group's halves likely share an XCD.
//   logits via GEMM on final h1 (== out1[len-1] since mask freezes h).

typedef __attribute__((ext_vector_type(8))) short bf16x8;
typedef __attribute__((ext_vector_type(4))) float f32x4;

#define T_STEPS 512
#define NBATCH  128
#define HID     512
#define INSZ    256

static __device__ __forceinline__ float bf2f(__hip_bfloat16 v) { return __bfloat162float(v); }
static __device__ __forceinline__ __hip_bfloat16 f2bf(float v) { return __float2bfloat16(v); }

union BF8 { bf16x8 v; unsigned short u[8]; };
static __device__ __forceinline__ unsigned short f2bfbits(float x) {
    __hip_bfloat16 b = __float2bfloat16(x);
    return *reinterpret_cast<unsigned short*>(&b);
}

// ---------------- dtype probe: even uint16s of fp32 data are random mantissa halves
__global__ void detect_dtype(const unsigned short* __restrict__ x, unsigned int* __restrict__ dflag) {
    if (threadIdx.x == 0 && blockIdx.x == 0) {
        int sane = 0;
        for (int i = 0; i < 64; ++i) {
            unsigned short v = x[2 * i];
            unsigned int e = (v >> 7) & 0xFF;
            if (v == 0 || (e >= 0x60 && e <= 0x9F)) ++sane;
        }
        *dflag = (sane >= 48) ? 0u : 1u;  // 0 = bf16 data, 1 = fp32 data
    }
}

__global__ void to_bf16(const void* __restrict__ src, __hip_bfloat16* __restrict__ dst,
                        int n, const unsigned int* __restrict__ dflag) {
    bool f32 = *dflag != 0;
    int i = blockIdx.x * blockDim.x + threadIdx.x;
    if (i < n) dst[i] = f32 ? f2bf(((const float*)src)[i]) : ((const __hip_bfloat16*)src)[i];
}

__global__ void to_f32(const void* __restrict__ src, float* __restrict__ dst,
                       int n, const unsigned int* __restrict__ dflag) {
    bool f32 = *dflag != 0;
    int i = blockIdx.x * blockDim.x + threadIdx.x;
    if (i < n) dst[i] = f32 ? ((const float*)src)[i] : bf2f(((const __hip_bfloat16*)src)[i]);
}

// ---------------- GEMM: out[M][N] = A[M][K] @ W[N][K]^T + b1[N] (+ b2[N])
__global__ __launch_bounds__(256, 4) void gemm_bt64(
    const void* __restrict__ A, const __hip_bfloat16* __restrict__ W,
    const float* __restrict__ b1, const float* __restrict__ b2,
    void* __restrict__ out, int M, int N, int K,
    const int* __restrict__ lengths, const unsigned int* __restrict__ dflag,
    int aIsInput, int outIsOutput)
{
    const int r0 = blockIdx.y * 64;
    if (lengths) {  // rows are (t*128+n); a 64-row tile is one t, n0 in {0,64}; sorted desc.
        int t = r0 >> 7, n0 = r0 & 127;
        if (lengths[n0] <= t) return;
    }
    const bool f32in = (dflag != nullptr) && (*dflag != 0);
    const int c0 = blockIdx.x * 64;
    __shared__ short As[64 * 32];
    __shared__ short Bs[64 * 32];
    const int tid = threadIdx.x;
    const int lane = tid & 63, wave = tid >> 6;
    const int lrow = tid >> 2, lk = (tid & 3) * 8;
    const int q = (lane >> 4) & 3, l15 = lane & 15;

    f32x4 z = {0.f, 0.f, 0.f, 0.f};
    f32x4 acc[4];
#pragma unroll
    for (int m = 0; m < 4; ++m) acc[m] = z;

    for (int kk = 0; kk < K; kk += 32) {
        if (aIsInput && f32in) {
            const float* f = (const float*)A + (size_t)(r0 + lrow) * K + kk + lk;
            BF8 u;
#pragma unroll
            for (int i = 0; i < 8; ++i) u.u[i] = f2bfbits(f[i]);
            *(bf16x8*)&As[lrow * 32 + lk] = u.v;
        } else {
            *(bf16x8*)&As[lrow * 32 + lk] =
                *(const bf16x8*)((const __hip_bfloat16*)A + (size_t)(r0 + lrow) * K + kk + lk);
        }
        *(bf16x8*)&Bs[lrow * 32 + lk] = *(const bf16x8*)(W + (size_t)(c0 + lrow) * K + kk + lk);
        __syncthreads();
        bf16x8 bfrag = *(const bf16x8*)&Bs[(wave * 16 + l15) * 32 + q * 8];
#pragma unroll
        for (int m = 0; m < 4; ++m) {
            bf16x8 afrag = *(const bf16x8*)&As[(m * 16 + l15) * 32 + q * 8];
            acc[m] = __builtin_amdgcn_mfma_f32_16x16x32_bf16(afrag, bfrag, acc[m], 0, 0, 0);
        }
        __syncthreads();
    }
    const int col = c0 + wave * 16 + l15;
    float bias = b1[col] + (b2 ? b2[col] : 0.f);
#pragma unroll
    for (int m = 0; m < 4; ++m) {
#pragma unroll
        for (int r = 0; r < 4; ++r) {
            int row = r0 + m * 16 + q * 4 + r;
            float v = acc[m][r] + bias;
            if (outIsOutput && f32in) ((float*)out)[(size_t)row * N + col] = v;
            else ((__hip_bfloat16*)out)[(size_t)row * N + col] = f2bf(v);
        }
    }
}

// ---------------- recurrence: one layer. grid = 16 blocks (8 groups x 2 halves), 512 thr.
__global__ __launch_bounds__(512, 2) void rnn_recur(
    const __hip_bfloat16* __restrict__ xp,    // [T*128][512] bf16 (ws)
    const __hip_bfloat16* __restrict__ Whh,   // [512][512] bf16 (ws)
    const float* __restrict__ h0l,            // [128][512] fp32 (ws)
    const int* __restrict__ lengths,          // [128] sorted desc
    __hip_bfloat16* __restrict__ hbuf,        // [2 parity][128][512]
    __hip_bfloat16* __restrict__ out0,        // [T*128][512] or nullptr
    float* __restrict__ hf32,                 // [128][512] final h (fp32)
    __hip_bfloat16* __restrict__ hfbf,        // [128][512] final h (bf16)
    unsigned int* __restrict__ flags)         // [8 groups][2 parts][520]
{
    const int gb = blockIdx.x & 7, p = (blockIdx.x >> 3) & 1;  // (g, g+8) pairing
    const int tid = threadIdx.x, lane = tid & 63, wave = tid >> 6;
    const int q = (lane >> 4) & 3, l15 = lane & 15;
    const int colBase = p * 256 + wave * 32;
    const int s0 = gb * 16;
    __shared__ short hlds[16 * 520];

    // persistent B fragments: Whh[j][k] for j in [colBase, colBase+32)
    bf16x8 bfr[2][16];
#pragma unroll
    for (int tau = 0; tau < 2; ++tau)
#pragma unroll
        for (int c = 0; c < 16; ++c)
            bfr[tau][c] = *(const bf16x8*)(Whh + (size_t)(colBase + tau * 16 + l15) * HID + c * 32 + q * 8);

    int len_r[4];
#pragma unroll
    for (int r = 0; r < 4; ++r) len_r[r] = lengths[s0 + q * 4 + r];

    float cur[2][4];
#pragma unroll
    for (int tau = 0; tau < 2; ++tau)
#pragma unroll
        for (int r = 0; r < 4; ++r)
            cur[tau][r] = h0l[(size_t)(s0 + q * 4 + r) * HID + colBase + tau * 16 + l15];

    // publish S_0 (own col-half, all 16 samples) into parity 0
#pragma unroll
    for (int tau = 0; tau < 2; ++tau)
#pragma unroll
        for (int r = 0; r < 4; ++r)
            hbuf[(size_t)(s0 + q * 4 + r) * HID + colBase + tau * 16 + l15] = f2bf(cur[tau][r]);
    __threadfence();
    __syncthreads();
    unsigned int* fl = flags + gb * (2 * 520);
    unsigned int* fOwn = fl + p * 520;
    unsigned int* fOther = fl + (1 - p) * 520;
    if (tid == 0) __hip_atomic_store(&fOwn[0], 1u, __ATOMIC_RELEASE, __HIP_MEMORY_SCOPE_AGENT);

    const int Tg = lengths[s0];       // group max length (sorted desc); same for both halves
    const int srow = tid >> 5;
    const int sk = (tid & 31) * 16;

    for (int t = 0; t < Tg; ++t) {
        long guard = 0;
        while (__hip_atomic_load(&fOther[t], __ATOMIC_ACQUIRE, __HIP_MEMORY_SCOPE_AGENT) == 0u) {
            if (++guard > (1L << 28)) break;  // failsafe against deadlock-hang
        }
        __syncthreads();
        {
            const __hip_bfloat16* hsrc = hbuf + (size_t)(t & 1) * NBATCH * HID + (size_t)s0 * HID;
            bf16x8 v0 = *(const bf16x8*)(hsrc + srow * HID + sk);
            bf16x8 v1 = *(const bf16x8*)(hsrc + srow * HID + sk + 8);
            *(bf16x8*)&hlds[srow * 520 + sk] = v0;
            *(bf16x8*)&hlds[srow * 520 + sk + 8] = v1;
        }
        __syncthreads();

        const __hip_bfloat16* xprow = xp + ((size_t)t * NBATCH + s0) * HID;
        float xv[2][4];
#pragma unroll
        for (int tau = 0; tau < 2; ++tau)
#pragma unroll
            for (int r = 0; r < 4; ++r)
                xv[tau][r] = bf2f(xprow[(size_t)(q * 4 + r) * HID + colBase + tau * 16 + l15]);

        f32x4 zz = {0.f, 0.f, 0.f, 0.f};
        f32x4 acc[2] = {zz, zz};
#pragma unroll
        for (int c = 0; c < 16; ++c) {
            bf16x8 a = *(const bf16x8*)&hlds[l15 * 520 + c * 32 + q * 8];
            acc[0] = __builtin_amdgcn_mfma_f32_16x16x32_bf16(a, bfr[0][c], acc[0], 0, 0, 0);
            acc[1] = __builtin_amdgcn_mfma_f32_16x16x32_bf16(a, bfr[1][c], acc[1], 0, 0, 0);
        }

        __hip_bfloat16* hdst = hbuf + (size_t)((t + 1) & 1) * NBATCH * HID;
#pragma unroll
        for (int tau = 0; tau < 2; ++tau) {
#pragma unroll
            for (int r = 0; r < 4; ++r) {
                int sl = q * 4 + r;
                int j = colBase + tau * 16 + l15;
                float hnew = tanhf(acc[tau][r] + xv[tau][r]);
                float val = (t < len_r[r]) ? hnew : cur[tau][r];
                if (t <= len_r[r]) {
                    __hip_bfloat16 vb = f2bf(val);
                    hdst[(size_t)(s0 + sl) * HID + j] = vb;
                    if (out0) out0[((size_t)t * NBATCH + s0 + sl) * HID + j] = vb;
                }
                cur[tau][r] = val;
            }
        }
        __threadfence();
        __syncthreads();
        if (tid == 0) __hip_atomic_store(&fOwn[t + 1], 1u, __ATOMIC_RELEASE, __HIP_MEMORY_SCOPE_AGENT);
    }

#pragma unroll
    for (int tau = 0; tau < 2; ++tau)
#pragma unroll
        for (int r = 0; r < 4; ++r) {
            size_t idx = (size_t)(s0 + q * 4 + r) * HID + colBase + tau * 16 + l15;
            hf32[idx] = cur[tau][r];
            hfbf[idx] = f2bf(cur[tau][r]);
        }
}

__global__ void copy_h(const float* __restrict__ src, void* __restrict__ d_out,
                       const unsigned int* __restrict__ dflag) {
    bool f32 = *dflag != 0;
    for (int i = blockIdx.x * blockDim.x + threadIdx.x; i < 2 * NBATCH * HID;
         i += gridDim.x * blockDim.x) {
        if (f32) ((float*)d_out + NBATCH * 128)[i] = src[i];
        else     ((__hip_bfloat16*)d_out + NBATCH * 128)[i] = f2bf(src[i]);
    }
}

extern "C" void kernel_launch(void* const* d_in, const int* in_sizes, int n_in,
                              void* d_out, int out_size, void* d_ws, size_t ws_size,
                              hipStream_t stream) {
    const void* x    = d_in[0];
    const void* h0   = d_in[1];
    const int*  lens = (const int*)d_in[2];
    const void* Wih0 = d_in[3];
    const void* bih0 = d_in[4];
    const void* Whh0 = d_in[5];
    const void* bhh0 = d_in[6];
    const void* Wih1 = d_in[7];
    const void* bih1 = d_in[8];
    const void* Whh1 = d_in[9];
    const void* bhh1 = d_in[10];
    const void* Wfc  = d_in[11];
    const void* bfc  = d_in[12];

    const size_t MROWS = (size_t)T_STEPS * NBATCH;          // 65536
    size_t off = 0;
    auto take = [&](size_t bytes) { size_t o = off; off += (bytes + 255) & ~255ull; return o; };
    const size_t off_xp   = take(MROWS * HID * 2);          // 64 MB bf16
    const size_t off_out0 = take(MROWS * HID * 2);          // 64 MB bf16
    const size_t off_hbuf = take(2ull * 2 * NBATCH * HID * 2);
    const size_t off_hf32 = take(2ull * NBATCH * HID * 4);
    const size_t off_hfbf = take(2ull * NBATCH * HID * 2);
    const size_t FLAG_INTS = 2ull * 8 * 2 * 520;
    const size_t off_flag = take(FLAG_INTS * 4);
    const size_t off_dfl  = take(256);
    const size_t off_wi0  = take((size_t)HID * INSZ * 2);
    const size_t off_wh0  = take((size_t)HID * HID * 2);
    const size_t off_wi1  = take((size_t)HID * HID * 2);
    const size_t off_wh1  = take((size_t)HID * HID * 2);
    const size_t off_wfc  = take(128ull * HID * 2);
    const size_t off_b0   = take(HID * 4);   // bih0+bhh0 handled as two arrays
    const size_t off_b1   = take(HID * 4);
    const size_t off_b2   = take(HID * 4);
    const size_t off_b3   = take(HID * 4);
    const size_t off_bf   = take(128 * 4);
    const size_t off_h0f  = take(2ull * NBATCH * HID * 4);
    if (ws_size < off) return;  // workspace too small

    char* ws = (char*)d_ws;
    __hip_bfloat16* xp    = (__hip_bfloat16*)(ws + off_xp);
    __hip_bfloat16* out0  = (__hip_bfloat16*)(ws + off_out0);
    __hip_bfloat16* hbuf  = (__hip_bfloat16*)(ws + off_hbuf);
    float*          hf32  = (float*)(ws + off_hf32);
    __hip_bfloat16* hfbf  = (__hip_bfloat16*)(ws + off_hfbf);
    unsigned int*   flags = (unsigned int*)(ws + off_flag);
    unsigned int*   dflag = (unsigned int*)(ws + off_dfl);
    __hip_bfloat16* wi0   = (__hip_bfloat16*)(ws + off_wi0);
    __hip_bfloat16* wh0   = (__hip_bfloat16*)(ws + off_wh0);
    __hip_bfloat16* wi1   = (__hip_bfloat16*)(ws + off_wi1);
    __hip_bfloat16* wh1   = (__hip_bfloat16*)(ws + off_wh1);
    __hip_bfloat16* wfc   = (__hip_bfloat16*)(ws + off_wfc);
    float* b0f = (float*)(ws + off_b0);
    float* b1f = (float*)(ws + off_b1);
    float* b2f = (float*)(ws + off_b2);
    float* b3f = (float*)(ws + off_b3);
    float* bff = (float*)(ws + off_bf);
    float* h0f = (float*)(ws + off_h0f);

    hipMemsetAsync(flags, 0, FLAG_INTS * 4, stream);
    detect_dtype<<<1, 64, 0, stream>>>((const unsigned short*)x, dflag);

    to_bf16<<<(HID * INSZ + 255) / 256, 256, 0, stream>>>(Wih0, wi0, HID * INSZ, dflag);
    to_bf16<<<(HID * HID + 255) / 256, 256, 0, stream>>>(Whh0, wh0, HID * HID, dflag);
    to_bf16<<<(HID * HID + 255) / 256, 256, 0, stream>>>(Wih1, wi1, HID * HID, dflag);
    to_bf16<<<(HID * HID + 255) / 256, 256, 0, stream>>>(Whh1, wh1, HID * HID, dflag);
    to_bf16<<<(128 * HID + 255) / 256, 256, 0, stream>>>(Wfc, wfc, 128 * HID, dflag);
    to_f32<<<2, 256, 0, stream>>>(bih0, b0f, HID, dflag);
    to_f32<<<2, 256, 0, stream>>>(bhh0, b1f, HID, dflag);
    to_f32<<<2, 256, 0, stream>>>(bih1, b2f, HID, dflag);
    to_f32<<<2, 256, 0, stream>>>(bhh1, b3f, HID, dflag);
    to_f32<<<1, 128, 0, stream>>>(bfc, bff, 128, dflag);
    to_f32<<<(2 * NBATCH * HID + 255) / 256, 256, 0, stream>>>(h0, h0f, 2 * NBATCH * HID, dflag);

    // layer 0 input GEMM: xp0 = x @ Wih0^T + bih0 + bhh0
    gemm_bt64<<<dim3(HID / 64, MROWS / 64), 256, 0, stream>>>(
        x, wi0, b0f, b1f, xp, (int)MROWS, HID, INSZ, lens, dflag, 1, 0);
    // layer 0 recurrence
    rnn_recur<<<16, 512, 0, stream>>>(
        xp, wh0, h0f, lens, hbuf, out0, hf32, hfbf, flags);
    // layer 1 input GEMM: xp1 = out0 @ Wih1^T + bih1 + bhh1 (reuse xp region)
    gemm_bt64<<<dim3(HID / 64, MROWS / 64), 256, 0, stream>>>(
        out0, wi1, b2f, b3f, xp, (int)MROWS, HID, HID, lens, dflag, 0, 0);
    // layer 1 recurrence (no out materialization needed)
    rnn_recur<<<16, 512, 0, stream>>>(
        xp, wh1, h0f + (size_t)NBATCH * HID, lens,
        hbuf + 2ull * NBATCH * HID, nullptr,
        hf32 + (size_t)NBATCH * HID, hfbf + (size_t)NBATCH * HID,
        flags + 8 * 2 * 520);
    // logits = h1_final @ Wfc^T + bfc   (last valid out1 row == frozen final h1)
    gemm_bt64<<<dim3(2, 2), 256, 0, stream>>>(
        hfbf + (size_t)NBATCH * HID, wfc, bff, nullptr,
        d_out, NBATCH, 128, HID, nullptr, dflag, 0, 1);
    // h outputs
    copy_h<<<64, 256, 0, stream>>>(hf32, d_out, dflag);
}

// Round 3
// 4528.247 us; speedup vs baseline: 1.6209x; 1.6209x over previous
//
#include <hip/hip_runtime.h>
#include <hip/hip_bf16.h>

// R3: tagged-word exchange replaces fence+flag handshake.
//   rnn_recur: 16 blocks = 8 groups x 2 col-halves. Whh half in VGPR/AGPR B-frags.
//   Per step, each block publishes its computed h-half as u32 (tag<<16 | bf16)
//   via RELAXED agent-scope atomics (no wbl2/inv), partner polls tags directly.
//   Own half stays in double-buffered LDS. t=0 staged from h0 (no handshake).
//   Race-freedom: publish(S_{t+1}) is data-dependent on poll(S_t); parity slots +
//   one block barrier/step make slot overwrite safe (see derivation in journal).

typedef __attribute__((ext_vector_type(8))) short bf16x8;
typedef __attribute__((ext_vector_type(4))) float f32x4;

#define T_STEPS 512
#define NBATCH  128
#define HID     512
#define INSZ    256
#define LROW    520   // LDS row stride (shorts)

static __device__ __forceinline__ float bf2f(__hip_bfloat16 v) { return __bfloat162float(v); }
static __device__ __forceinline__ __hip_bfloat16 f2bf(float v) { return __float2bfloat16(v); }

union BF8 { bf16x8 v; unsigned short u[8]; };
static __device__ __forceinline__ unsigned short f2bfbits(float x) {
    __hip_bfloat16 b = __float2bfloat16(x);
    return *reinterpret_cast<unsigned short*>(&b);
}

// ---------------- dtype probe: even uint16s of fp32 data are random mantissa halves
__global__ void detect_dtype(const unsigned short* __restrict__ x, unsigned int* __restrict__ dflag) {
    if (threadIdx.x == 0 && blockIdx.x == 0) {
        int sane = 0;
        for (int i = 0; i < 64; ++i) {
            unsigned short v = x[2 * i];
            unsigned int e = (v >> 7) & 0xFF;
            if (v == 0 || (e >= 0x60 && e <= 0x9F)) ++sane;
        }
        *dflag = (sane >= 48) ? 0u : 1u;  // 0 = bf16 data, 1 = fp32 data
    }
}

__global__ void to_bf16(const void* __restrict__ src, __hip_bfloat16* __restrict__ dst,
                        int n, const unsigned int* __restrict__ dflag) {
    bool f32 = *dflag != 0;
    int i = blockIdx.x * blockDim.x + threadIdx.x;
    if (i < n) dst[i] = f32 ? f2bf(((const float*)src)[i]) : ((const __hip_bfloat16*)src)[i];
}

__global__ void to_f32(const void* __restrict__ src, float* __restrict__ dst,
                       int n, const unsigned int* __restrict__ dflag) {
    bool f32 = *dflag != 0;
    int i = blockIdx.x * blockDim.x + threadIdx.x;
    if (i < n) dst[i] = f32 ? ((const float*)src)[i] : bf2f(((const __hip_bfloat16*)src)[i]);
}

// ---------------- GEMM: out[M][N] = A[M][K] @ W[N][K]^T + b1[N] (+ b2[N])
__global__ __launch_bounds__(256, 4) void gemm_bt64(
    const void* __restrict__ A, const __hip_bfloat16* __restrict__ W,
    const float* __restrict__ b1, const float* __restrict__ b2,
    void* __restrict__ out, int M, int N, int K,
    const int* __restrict__ lengths, const unsigned int* __restrict__ dflag,
    int aIsInput, int outIsOutput)
{
    const int r0 = blockIdx.y * 64;
    if (lengths) {  // rows are (t*128+n); a 64-row tile is one t, n0 in {0,64}; sorted desc.
        int t = r0 >> 7, n0 = r0 & 127;
        if (lengths[n0] <= t) return;
    }
    const bool f32in = (dflag != nullptr) && (*dflag != 0);
    const int c0 = blockIdx.x * 64;
    __shared__ short As[64 * 32];
    __shared__ short Bs[64 * 32];
    const int tid = threadIdx.x;
    const int lane = tid & 63, wave = tid >> 6;
    const int lrow = tid >> 2, lk = (tid & 3) * 8;
    const int q = (lane >> 4) & 3, l15 = lane & 15;

    f32x4 z = {0.f, 0.f, 0.f, 0.f};
    f32x4 acc[4];
#pragma unroll
    for (int m = 0; m < 4; ++m) acc[m] = z;

    for (int kk = 0; kk < K; kk += 32) {
        if (aIsInput && f32in) {
            const float* f = (const float*)A + (size_t)(r0 + lrow) * K + kk + lk;
            BF8 u;
#pragma unroll
            for (int i = 0; i < 8; ++i) u.u[i] = f2bfbits(f[i]);
            *(bf16x8*)&As[lrow * 32 + lk] = u.v;
        } else {
            *(bf16x8*)&As[lrow * 32 + lk] =
                *(const bf16x8*)((const __hip_bfloat16*)A + (size_t)(r0 + lrow) * K + kk + lk);
        }
        *(bf16x8*)&Bs[lrow * 32 + lk] = *(const bf16x8*)(W + (size_t)(c0 + lrow) * K + kk + lk);
        __syncthreads();
        bf16x8 bfrag = *(const bf16x8*)&Bs[(wave * 16 + l15) * 32 + q * 8];
#pragma unroll
        for (int m = 0; m < 4; ++m) {
            bf16x8 afrag = *(const bf16x8*)&As[(m * 16 + l15) * 32 + q * 8];
            acc[m] = __builtin_amdgcn_mfma_f32_16x16x32_bf16(afrag, bfrag, acc[m], 0, 0, 0);
        }
        __syncthreads();
    }
    const int col = c0 + wave * 16 + l15;
    float bias = b1[col] + (b2 ? b2[col] : 0.f);
#pragma unroll
    for (int m = 0; m < 4; ++m) {
#pragma unroll
        for (int r = 0; r < 4; ++r) {
            int row = r0 + m * 16 + q * 4 + r;
            float v = acc[m][r] + bias;
            if (outIsOutput && f32in) ((float*)out)[(size_t)row * N + col] = v;
            else ((__hip_bfloat16*)out)[(size_t)row * N + col] = f2bf(v);
        }
    }
}

// ---------------- recurrence: one layer. grid = 16 blocks (8 groups x 2 halves), 512 thr.
// Blocks b and b+8 form a pair (same group, halves 0/1) — likely same XCD under
// round-robin dispatch (perf only; correctness is scope-safe either way).
__global__ __launch_bounds__(512, 2) void rnn_recur(
    const __hip_bfloat16* __restrict__ xp,    // [T*128][512] bf16 (ws)
    const __hip_bfloat16* __restrict__ Whh,   // [512][512] bf16 (ws)
    const float* __restrict__ h0l,            // [128][512] fp32 (ws)
    const int* __restrict__ lengths,          // [128] sorted desc
    __hip_bfloat16* __restrict__ out0,        // [T*128][512] or nullptr
    float* __restrict__ hf32,                 // [128][512] final h (fp32)
    __hip_bfloat16* __restrict__ hfbf,        // [128][512] final h (bf16)
    unsigned int* __restrict__ ex)            // [8 groups][2 slots][2 p][16*256] u32
{
    const int gb = blockIdx.x & 7, p = (blockIdx.x >> 3) & 1;
    const int tid = threadIdx.x, lane = tid & 63, wave = tid >> 6;
    const int q = (lane >> 4) & 3, l15 = lane & 15;
    const int colBase = p * 256 + wave * 32;   // this wave's 32 output columns
    const int s0 = gb * 16;
    const int pcPart = (1 - p) * 256;          // partner's column base
    __shared__ short hlds[2 * 16 * LROW];      // double-buffered h (16 samples x 512 cols)

    // persistent B fragments: Whh[j][k] for j in [colBase, colBase+32)
    bf16x8 bfr[2][16];
#pragma unroll
    for (int tau = 0; tau < 2; ++tau)
#pragma unroll
        for (int c = 0; c < 16; ++c)
            bfr[tau][c] = *(const bf16x8*)(Whh + (size_t)(colBase + tau * 16 + l15) * HID + c * 32 + q * 8);

    int len_r[4];
#pragma unroll
    for (int r = 0; r < 4; ++r) len_r[r] = lengths[s0 + q * 4 + r];

    float cur[2][4];
#pragma unroll
    for (int tau = 0; tau < 2; ++tau)
#pragma unroll
        for (int r = 0; r < 4; ++r)
            cur[tau][r] = h0l[(size_t)(s0 + q * 4 + r) * HID + colBase + tau * 16 + l15];

    // stage FULL S_0 (both halves) from h0 directly — no handshake at t=0
    {
        const int sr = tid >> 5, cb = (tid & 31) * 16;  // 16 cols per thread
        const float* src = h0l + (size_t)(s0 + sr) * HID + cb;
        BF8 u0, u1;
#pragma unroll
        for (int i = 0; i < 8; ++i) { u0.u[i] = f2bfbits(src[i]); u1.u[i] = f2bfbits(src[8 + i]); }
        *(bf16x8*)&hlds[sr * LROW + cb] = u0.v;
        *(bf16x8*)&hlds[sr * LROW + cb + 8] = u1.v;
    }
    __syncthreads();

    const int Tg = lengths[s0];   // group max length; same for both halves
    const int sr = tid >> 5, wc = (tid & 31) * 8;
    unsigned int* exg = ex + (size_t)gb * 2 * 2 * 4096;

    for (int t = 0; t < Tg; ++t) {
        const int cb_ = t & 1, nb = (t + 1) & 1;

        // xp for this step (independent of h — issue early)
        const __hip_bfloat16* xprow = xp + ((size_t)t * NBATCH + s0) * HID;
        float xv[2][4];
#pragma unroll
        for (int tau = 0; tau < 2; ++tau)
#pragma unroll
            for (int r = 0; r < 4; ++r)
                xv[tau][r] = bf2f(xprow[(size_t)(q * 4 + r) * HID + colBase + tau * 16 + l15]);

        f32x4 zz = {0.f, 0.f, 0.f, 0.f};
        f32x4 acc[2] = {zz, zz};
#pragma unroll
        for (int c = 0; c < 16; ++c) {
            bf16x8 a = *(const bf16x8*)&hlds[cb_ * 16 * LROW + l15 * LROW + c * 32 + q * 8];
            acc[0] = __builtin_amdgcn_mfma_f32_16x16x32_bf16(a, bfr[0][c], acc[0], 0, 0, 0);
            acc[1] = __builtin_amdgcn_mfma_f32_16x16x32_bf16(a, bfr[1][c], acc[1], 0, 0, 0);
        }

        // compute h_{t+1}; publish own half (tagged u32, relaxed agent atomics);
        // keep own half in LDS buf nb; optional out0 store
        const unsigned int tag = (unsigned int)(t + 1);
        unsigned int* exw = exg + (nb * 2 + p) * 4096;
#pragma unroll
        for (int tau = 0; tau < 2; ++tau) {
#pragma unroll
            for (int r = 0; r < 4; ++r) {
                int sl = q * 4 + r;
                float hnew = tanhf(acc[tau][r] + xv[tau][r]);
                float val = (t < len_r[r]) ? hnew : cur[tau][r];
                cur[tau][r] = val;
                unsigned short bits = f2bfbits(val);
                __hip_atomic_store(&exw[sl * 256 + wave * 32 + tau * 16 + l15],
                                   (tag << 16) | (unsigned int)bits,
                                   __ATOMIC_RELAXED, __HIP_MEMORY_SCOPE_AGENT);
                hlds[nb * 16 * LROW + sl * LROW + colBase + tau * 16 + l15] = (short)bits;
                if (out0 && t < len_r[r]) {
                    __hip_bfloat16 vb = f2bf(val);
                    out0[((size_t)t * NBATCH + s0 + sl) * HID + colBase + tau * 16 + l15] = vb;
                }
            }
        }

        // poll partner's half of S_{t+1} (skip after last step)
        if (t + 1 < Tg) {
            const unsigned int* exr = exg + (nb * 2 + (1 - p)) * 4096 + sr * 256 + wc;
            unsigned int v[8];
            bool ok;
            int guard = 0;
            do {
                ok = true;
#pragma unroll
                for (int i = 0; i < 8; ++i)
                    v[i] = __hip_atomic_load(&exr[i], __ATOMIC_RELAXED, __HIP_MEMORY_SCOPE_AGENT);
#pragma unroll
                for (int i = 0; i < 8; ++i) ok &= ((v[i] >> 16) == tag);
            } while (!ok && ++guard < (1 << 26));
            BF8 u;
#pragma unroll
            for (int i = 0; i < 8; ++i) u.u[i] = (unsigned short)(v[i] & 0xFFFF);
            *(bf16x8*)&hlds[nb * 16 * LROW + sr * LROW + pcPart + wc] = u.v;
        }
        __syncthreads();
    }

    // finals
#pragma unroll
    for (int tau = 0; tau < 2; ++tau)
#pragma unroll
        for (int r = 0; r < 4; ++r) {
            size_t idx = (size_t)(s0 + q * 4 + r) * HID + colBase + tau * 16 + l15;
            hf32[idx] = cur[tau][r];
            hfbf[idx] = f2bf(cur[tau][r]);
        }
}

__global__ void copy_h(const float* __restrict__ src, void* __restrict__ d_out,
                       const unsigned int* __restrict__ dflag) {
    bool f32 = *dflag != 0;
    for (int i = blockIdx.x * blockDim.x + threadIdx.x; i < 2 * NBATCH * HID;
         i += gridDim.x * blockDim.x) {
        if (f32) ((float*)d_out + NBATCH * 128)[i] = src[i];
        else     ((__hip_bfloat16*)d_out + NBATCH * 128)[i] = f2bf(src[i]);
    }
}

extern "C" void kernel_launch(void* const* d_in, const int* in_sizes, int n_in,
                              void* d_out, int out_size, void* d_ws, size_t ws_size,
                              hipStream_t stream) {
    const void* x    = d_in[0];
    const void* h0   = d_in[1];
    const int*  lens = (const int*)d_in[2];
    const void* Wih0 = d_in[3];
    const void* bih0 = d_in[4];
    const void* Whh0 = d_in[5];
    const void* bhh0 = d_in[6];
    const void* Wih1 = d_in[7];
    const void* bih1 = d_in[8];
    const void* Whh1 = d_in[9];
    const void* bhh1 = d_in[10];
    const void* Wfc  = d_in[11];
    const void* bfc  = d_in[12];

    const size_t MROWS = (size_t)T_STEPS * NBATCH;          // 65536
    size_t off = 0;
    auto take = [&](size_t bytes) { size_t o = off; off += (bytes + 255) & ~255ull; return o; };
    const size_t off_xp   = take(MROWS * HID * 2);          // 64 MB bf16
    const size_t off_out0 = take(MROWS * HID * 2);          // 64 MB bf16
    const size_t off_ex   = take(2ull * 8 * 2 * 2 * 4096 * 4);  // 2 layers x exchange
    const size_t off_hf32 = take(2ull * NBATCH * HID * 4);
    const size_t off_hfbf = take(2ull * NBATCH * HID * 2);
    const size_t off_dfl  = take(256);
    const size_t off_wi0  = take((size_t)HID * INSZ * 2);
    const size_t off_wh0  = take((size_t)HID * HID * 2);
    const size_t off_wi1  = take((size_t)HID * HID * 2);
    const size_t off_wh1  = take((size_t)HID * HID * 2);
    const size_t off_wfc  = take(128ull * HID * 2);
    const size_t off_b0   = take(HID * 4);
    const size_t off_b1   = take(HID * 4);
    const size_t off_b2   = take(HID * 4);
    const size_t off_b3   = take(HID * 4);
    const size_t off_bf   = take(128 * 4);
    const size_t off_h0f  = take(2ull * NBATCH * HID * 4);
    if (ws_size < off) return;  // workspace too small

    char* ws = (char*)d_ws;
    __hip_bfloat16* xp    = (__hip_bfloat16*)(ws + off_xp);
    __hip_bfloat16* out0  = (__hip_bfloat16*)(ws + off_out0);
    unsigned int*   ex    = (unsigned int*)(ws + off_ex);
    float*          hf32  = (float*)(ws + off_hf32);
    __hip_bfloat16* hfbf  = (__hip_bfloat16*)(ws + off_hfbf);
    unsigned int*   dflag = (unsigned int*)(ws + off_dfl);
    __hip_bfloat16* wi0   = (__hip_bfloat16*)(ws + off_wi0);
    __hip_bfloat16* wh0   = (__hip_bfloat16*)(ws + off_wh0);
    __hip_bfloat16* wi1   = (__hip_bfloat16*)(ws + off_wi1);
    __hip_bfloat16* wh1   = (__hip_bfloat16*)(ws + off_wh1);
    __hip_bfloat16* wfc   = (__hip_bfloat16*)(ws + off_wfc);
    float* b0f = (float*)(ws + off_b0);
    float* b1f = (float*)(ws + off_b1);
    float* b2f = (float*)(ws + off_b2);
    float* b3f = (float*)(ws + off_b3);
    float* bff = (float*)(ws + off_bf);
    float* h0f = (float*)(ws + off_h0f);

    // NOTE: no memset of `ex` needed — 0xAA poison tag (0xAAAA) matches no step tag (1..512).
    detect_dtype<<<1, 64, 0, stream>>>((const unsigned short*)x, dflag);

    to_bf16<<<(HID * INSZ + 255) / 256, 256, 0, stream>>>(Wih0, wi0, HID * INSZ, dflag);
    to_bf16<<<(HID * HID + 255) / 256, 256, 0, stream>>>(Whh0, wh0, HID * HID, dflag);
    to_bf16<<<(HID * HID + 255) / 256, 256, 0, stream>>>(Wih1, wi1, HID * HID, dflag);
    to_bf16<<<(HID * HID + 255) / 256, 256, 0, stream>>>(Whh1, wh1, HID * HID, dflag);
    to_bf16<<<(128 * HID + 255) / 256, 256, 0, stream>>>(Wfc, wfc, 128 * HID, dflag);
    to_f32<<<2, 256, 0, stream>>>(bih0, b0f, HID, dflag);
    to_f32<<<2, 256, 0, stream>>>(bhh0, b1f, HID, dflag);
    to_f32<<<2, 256, 0, stream>>>(bih1, b2f, HID, dflag);
    to_f32<<<2, 256, 0, stream>>>(bhh1, b3f, HID, dflag);
    to_f32<<<1, 128, 0, stream>>>(bfc, bff, 128, dflag);
    to_f32<<<(2 * NBATCH * HID + 255) / 256, 256, 0, stream>>>(h0, h0f, 2 * NBATCH * HID, dflag);

    // layer 0 input GEMM: xp0 = x @ Wih0^T + bih0 + bhh0
    gemm_bt64<<<dim3(HID / 64, MROWS / 64), 256, 0, stream>>>(
        x, wi0, b0f, b1f, xp, (int)MROWS, HID, INSZ, lens, dflag, 1, 0);
    // layer 0 recurrence
    rnn_recur<<<16, 512, 0, stream>>>(
        xp, wh0, h0f, lens, out0, hf32, hfbf, ex);
    // layer 1 input GEMM: xp1 = out0 @ Wih1^T + bih1 + bhh1 (reuse xp region)
    gemm_bt64<<<dim3(HID / 64, MROWS / 64), 256, 0, stream>>>(
        out0, wi1, b2f, b3f, xp, (int)MROWS, HID, HID, lens, dflag, 0, 0);
    // layer 1 recurrence (no out materialization needed)
    rnn_recur<<<16, 512, 0, stream>>>(
        xp, wh1, h0f + (size_t)NBATCH * HID, lens, nullptr,
        hf32 + (size_t)NBATCH * HID, hfbf + (size_t)NBATCH * HID,
        ex + 8ull * 2 * 2 * 4096);
    // logits = h1_final @ Wfc^T + bfc   (last valid out1 row == frozen final h1)
    gemm_bt64<<<dim3(2, 2), 256, 0, stream>>>(
        hfbf + (size_t)NBATCH * HID, wfc, bff, nullptr,
        d_out, NBATCH, 128, HID, nullptr, dflag, 0, 1);
    // h outputs
    copy_h<<<64, 256, 0, stream>>>(hf32, d_out, dflag);
}